// Round 1
// baseline (955.126 us; speedup 1.0000x reference)
//
#include <hip/hip_runtime.h>
#include <math.h>

#define B_ 8
#define M_ 4096
#define D_ 1024
#define N_ 64
#define P_ 2
#define NP_ 128
#define TEMP_ 0.1f
#define EPS_ 1e-12f

// ---------------- phi normalization: phin[d][np] = scale * phi[d][np] / ||phi[:,np]|| ----------------
__global__ void k_phin(const float* __restrict__ phi, const float* __restrict__ scale,
                       float* __restrict__ phin) {
    int np = blockIdx.x;
    int tid = threadIdx.x;
    float ss = 0.f;
    for (int d = tid; d < D_; d += 256) {
        float v = phi[d * NP_ + np];
        ss += v * v;
    }
    __shared__ float red[256];
    red[tid] = ss;
    __syncthreads();
    for (int s = 128; s > 0; s >>= 1) {
        if (tid < s) red[tid] += red[tid + s];
        __syncthreads();
    }
    float inv = scale[0] / fmaxf(sqrtf(red[0]), EPS_);
    for (int d = tid; d < D_; d += 256) {
        phin[d * NP_ + np] = phi[d * NP_ + np] * inv;
    }
}

// ---------------- row inv-norms of x (folded with 1/TEMP) ----------------
__global__ void k_rownorm(const float* __restrict__ x, float* __restrict__ rinv) {
    int wave = threadIdx.x >> 6;
    int lane = threadIdx.x & 63;
    long long row = (long long)blockIdx.x * 4 + wave;  // < B*M
    const float4* xr = (const float4*)(x + row * D_);
    float ss = 0.f;
#pragma unroll
    for (int it = 0; it < 4; ++it) {
        float4 v = xr[lane + 64 * it];
        ss += v.x * v.x + v.y * v.y + v.z * v.z + v.w * v.w;
    }
    for (int off = 32; off > 0; off >>= 1) ss += __shfl_down(ss, off);
    if (lane == 0) rinv[row] = 1.0f / (fmaxf(sqrtf(ss), EPS_) * TEMP_);
}

// ---------------- logits[b][m][np] = (x[b][m][:] . phin[:,np]) * rinv[b][m] ----------------
// tile: 64 m x 128 np, K-tile 32
__global__ __launch_bounds__(256) void k_logits(const float* __restrict__ x,
                                                const float* __restrict__ phin,
                                                const float* __restrict__ rinv,
                                                float* __restrict__ logits) {
    const int b = blockIdx.y;
    const int m0 = blockIdx.x * 64;
    const int tid = threadIdx.x, tx = tid & 31, ty = tid >> 5;
    __shared__ float xt[32][64];    // [k][m]  (transposed)
    __shared__ float pt[32][128];   // [k][np]
    float acc[8][4];
#pragma unroll
    for (int i = 0; i < 8; ++i)
#pragma unroll
        for (int q = 0; q < 4; ++q) acc[i][q] = 0.f;
    const float* xb = x + ((long long)b * M_ + m0) * D_;
    for (int k0 = 0; k0 < D_; k0 += 32) {
#pragma unroll
        for (int it = 0; it < 2; ++it) {
            int idx = tid + 256 * it;
            int row = idx >> 3, c4 = (idx & 7) * 4;
            float4 v = *(const float4*)(xb + (long long)row * D_ + k0 + c4);
            xt[c4 + 0][row] = v.x; xt[c4 + 1][row] = v.y;
            xt[c4 + 2][row] = v.z; xt[c4 + 3][row] = v.w;
        }
#pragma unroll
        for (int it = 0; it < 4; ++it) {
            int idx = tid + 256 * it;
            int row = idx >> 5, c4 = (idx & 31) * 4;
            *(float4*)(&pt[row][c4]) = *(const float4*)(phin + (k0 + row) * NP_ + c4);
        }
        __syncthreads();
#pragma unroll
        for (int k = 0; k < 32; ++k) {
            float4 p = *(const float4*)(&pt[k][tx * 4]);
            float4 a0 = *(const float4*)(&xt[k][ty * 8]);
            float4 a1 = *(const float4*)(&xt[k][ty * 8 + 4]);
            float am[8] = {a0.x, a0.y, a0.z, a0.w, a1.x, a1.y, a1.z, a1.w};
#pragma unroll
            for (int i = 0; i < 8; ++i) {
                acc[i][0] += am[i] * p.x;
                acc[i][1] += am[i] * p.y;
                acc[i][2] += am[i] * p.z;
                acc[i][3] += am[i] * p.w;
            }
        }
        __syncthreads();
    }
#pragma unroll
    for (int i = 0; i < 8; ++i) {
        int m = m0 + ty * 8 + i;
        float r = rinv[b * M_ + m];
        float4 o;
        o.x = acc[i][0] * r; o.y = acc[i][1] * r;
        o.z = acc[i][2] * r; o.w = acc[i][3] * r;
        *(float4*)(logits + ((long long)(b * M_ + m)) * NP_ + tx * 4) = o;
    }
}

// ---------------- column softmax stats (over m), stage 1: per 256-m chunk ----------------
__global__ void k_colstats1(const float* __restrict__ logits, float* __restrict__ pmax,
                            float* __restrict__ psum) {
    int b = blockIdx.y, ch = blockIdx.x;
    int np = threadIdx.x & 127, half = threadIdx.x >> 7;
    const float* base = logits + ((long long)(b * M_ + ch * 256 + half * 128)) * NP_ + np;
    float mx = -1e30f, sm = 0.f;
    for (int i = 0; i < 128; ++i) {
        float v = base[(long long)i * NP_];
        float nm = fmaxf(mx, v);
        sm = sm * __expf(mx - nm) + __expf(v - nm);
        mx = nm;
    }
    __shared__ float smx[2][128], ssm[2][128];
    smx[half][np] = mx;
    ssm[half][np] = sm;
    __syncthreads();
    if (half == 0) {
        float m2 = smx[1][np], s2 = ssm[1][np];
        float Mx = fmaxf(mx, m2);
        float S = sm * __expf(mx - Mx) + s2 * __expf(m2 - Mx);
        pmax[(b * 16 + ch) * NP_ + np] = Mx;
        psum[(b * 16 + ch) * NP_ + np] = S;
    }
}

// ---------------- column softmax stats, stage 2 ----------------
__global__ void k_colstats2(const float* __restrict__ pmax, const float* __restrict__ psum,
                            float* __restrict__ cmax, float* __restrict__ cinv) {
    int b = blockIdx.x, np = threadIdx.x;
    float Mx = -1e30f;
    for (int ch = 0; ch < 16; ++ch) Mx = fmaxf(Mx, pmax[(b * 16 + ch) * NP_ + np]);
    float S = 0.f;
    for (int ch = 0; ch < 16; ++ch)
        S += psum[(b * 16 + ch) * NP_ + np] * __expf(pmax[(b * 16 + ch) * NP_ + np] - Mx);
    cmax[b * NP_ + np] = Mx;
    cinv[b * NP_ + np] = 1.0f / S;
}

// ---------------- dval = exp(logits - cmax)*cinv (dispatch weights) ----------------
__global__ void k_dval(const float* __restrict__ logits, const float* __restrict__ cmax,
                       const float* __restrict__ cinv, float* __restrict__ dval) {
    long long idx = ((long long)blockIdx.x * 256 + threadIdx.x) * 4;
    int np = (int)(idx & 127);
    int b = (int)(idx >> 19);  // / (M_*NP_)
    const float4 l = *(const float4*)(logits + idx);
    float4 o;
    o.x = __expf(l.x - cmax[b * NP_ + np + 0]) * cinv[b * NP_ + np + 0];
    o.y = __expf(l.y - cmax[b * NP_ + np + 1]) * cinv[b * NP_ + np + 1];
    o.z = __expf(l.z - cmax[b * NP_ + np + 2]) * cinv[b * NP_ + np + 2];
    o.w = __expf(l.w - cmax[b * NP_ + np + 3]) * cinv[b * NP_ + np + 3];
    *(float4*)(dval + idx) = o;
}

// ---------------- xs[b][np][d] = sum_m dval[b][m][np] * x[b][m][d]  (split-K + atomics) ----------------
// tile: 128 np x 64 d, K-chunk 1024 m
__global__ __launch_bounds__(256) void k_xs(const float* __restrict__ x,
                                            const float* __restrict__ dval,
                                            float* __restrict__ xs) {
    const int dt = blockIdx.x;  // 16 tiles of 64 d
    const int mc = blockIdx.y;  // 4 chunks of 1024 m
    const int b = blockIdx.z;
    const int d0 = dt * 64;
    const int tid = threadIdx.x, tx = tid & 31, ty = tid >> 5;
    __shared__ float dtile[32][128];  // [k][np]
    __shared__ float xt[32][64];      // [k][d]
    float acc[4][8];
#pragma unroll
    for (int q = 0; q < 4; ++q)
#pragma unroll
        for (int i = 0; i < 8; ++i) acc[q][i] = 0.f;
    const float* xbase = x + ((long long)b * M_ + mc * 1024) * D_;
    const float* dbase = dval + ((long long)b * M_ + mc * 1024) * NP_;
    for (int k0 = 0; k0 < 1024; k0 += 32) {
#pragma unroll
        for (int it = 0; it < 4; ++it) {
            int idx = tid + 256 * it;
            int row = idx >> 5, c4 = (idx & 31) * 4;
            *(float4*)(&dtile[row][c4]) = *(const float4*)(dbase + (long long)(k0 + row) * NP_ + c4);
        }
#pragma unroll
        for (int it = 0; it < 2; ++it) {
            int idx = tid + 256 * it;
            int row = idx >> 4, c4 = (idx & 15) * 4;
            *(float4*)(&xt[row][c4]) = *(const float4*)(xbase + (long long)(k0 + row) * D_ + d0 + c4);
        }
        __syncthreads();
#pragma unroll
        for (int k = 0; k < 32; ++k) {
            float4 dv = *(const float4*)(&dtile[k][tx * 4]);
            float4 x0 = *(const float4*)(&xt[k][ty * 8]);
            float4 x1 = *(const float4*)(&xt[k][ty * 8 + 4]);
            float xm[8] = {x0.x, x0.y, x0.z, x0.w, x1.x, x1.y, x1.z, x1.w};
#pragma unroll
            for (int i = 0; i < 8; ++i) {
                acc[0][i] += dv.x * xm[i];
                acc[1][i] += dv.y * xm[i];
                acc[2][i] += dv.z * xm[i];
                acc[3][i] += dv.w * xm[i];
            }
        }
        __syncthreads();
    }
#pragma unroll
    for (int q = 0; q < 4; ++q)
#pragma unroll
        for (int i = 0; i < 8; ++i)
            atomicAdd(&xs[((long long)b * NP_ + tx * 4 + q) * D_ + d0 + ty * 8 + i], acc[q][i]);
}

// ---------------- ys[b][np][e] = xs[b][np][:] @ W[n] + bias[n]  (np = n*2+p) ----------------
// block: one expert n, 128-e tile, all 16 (b,p) rows
__global__ __launch_bounds__(256) void k_ys(const float* __restrict__ xs,
                                            const float* __restrict__ W,
                                            const float* __restrict__ bias,
                                            float* __restrict__ ys) {
    const int et = blockIdx.x;  // 8 tiles of 128 e
    const int n = blockIdx.y;   // 64
    const int e0 = et * 128;
    const int tid = threadIdx.x, tx = tid & 31, ty = tid >> 5;
    __shared__ float wt[32][128];  // [k][e]
    __shared__ float xst[16][32];  // [row][k]
    float acc[2][4];
#pragma unroll
    for (int j = 0; j < 2; ++j)
#pragma unroll
        for (int q = 0; q < 4; ++q) acc[j][q] = 0.f;
    const float* wbase = W + (long long)n * D_ * D_;
    for (int k0 = 0; k0 < D_; k0 += 32) {
#pragma unroll
        for (int it = 0; it < 4; ++it) {
            int idx = tid + 256 * it;
            int row = idx >> 5, c4 = (idx & 31) * 4;
            *(float4*)(&wt[row][c4]) = *(const float4*)(wbase + (long long)(k0 + row) * D_ + e0 + c4);
        }
        if (tid < 128) {
            int r = tid >> 3, c4 = (tid & 7) * 4;
            int bb = r >> 1, p = r & 1;
            *(float4*)(&xst[r][c4]) =
                *(const float4*)(xs + ((long long)bb * NP_ + n * 2 + p) * D_ + k0 + c4);
        }
        __syncthreads();
#pragma unroll
        for (int k = 0; k < 32; ++k) {
            float4 w4 = *(const float4*)(&wt[k][tx * 4]);
            float r0 = xst[ty * 2][k], r1 = xst[ty * 2 + 1][k];
            acc[0][0] += r0 * w4.x; acc[0][1] += r0 * w4.y;
            acc[0][2] += r0 * w4.z; acc[0][3] += r0 * w4.w;
            acc[1][0] += r1 * w4.x; acc[1][1] += r1 * w4.y;
            acc[1][2] += r1 * w4.z; acc[1][3] += r1 * w4.w;
        }
        __syncthreads();
    }
    float4 bv = *(const float4*)(bias + n * D_ + e0 + tx * 4);
#pragma unroll
    for (int j = 0; j < 2; ++j) {
        int r = ty * 2 + j;
        int bb = r >> 1, p = r & 1;
        float4 o;
        o.x = acc[j][0] + bv.x; o.y = acc[j][1] + bv.y;
        o.z = acc[j][2] + bv.z; o.w = acc[j][3] + bv.w;
        *(float4*)(ys + ((long long)bb * NP_ + n * 2 + p) * D_ + e0 + tx * 4) = o;
    }
}

// ---------------- y = rowsoftmax(logits) @ ys + x ----------------
// tile: 32 m x 128 d, K = 128 np (chunks of 32)
__global__ __launch_bounds__(256) void k_final(const float* __restrict__ logits,
                                               const float* __restrict__ ys,
                                               const float* __restrict__ x,
                                               float* __restrict__ out) {
    const int dt = blockIdx.x;  // 8 x 128 d
    const int mt = blockIdx.y;  // 128 x 32 m
    const int b = blockIdx.z;
    const int d0 = dt * 128, m0 = mt * 32;
    const int tid = threadIdx.x, tx = tid & 31, ty = tid >> 5;
    __shared__ float lt[32][128];  // logits -> exp values
    __shared__ float yt[32][128];  // ys chunk [k][d]
    __shared__ float rsum[32];
    __shared__ float red[32][8];
#pragma unroll
    for (int it = 0; it < 4; ++it) {
        int idx = tid + 256 * it;
        int row = idx >> 5, c4 = (idx & 31) * 4;
        *(float4*)(&lt[row][c4]) = *(const float4*)(logits + ((long long)(b * M_ + m0 + row)) * NP_ + c4);
    }
    __syncthreads();
    {
        int m = tid >> 3, sub = tid & 7;
        float mx = -1e30f;
#pragma unroll
        for (int i = 0; i < 16; ++i) mx = fmaxf(mx, lt[m][sub * 16 + i]);
        red[m][sub] = mx;
        __syncthreads();
        if (sub == 0) {
            float Mx = -1e30f;
#pragma unroll
            for (int j = 0; j < 8; ++j) Mx = fmaxf(Mx, red[m][j]);
            red[m][0] = Mx;  // reuse slot 0 for row max
        }
        __syncthreads();
        float Mx = red[m][0];
        __syncthreads();
        float s = 0.f;
#pragma unroll
        for (int i = 0; i < 16; ++i) {
            float e = __expf(lt[m][sub * 16 + i] - Mx);
            lt[m][sub * 16 + i] = e;
            s += e;
        }
        red[m][sub] = s;
        __syncthreads();
        if (sub == 0) {
            float S = 0.f;
#pragma unroll
            for (int j = 0; j < 8; ++j) S += red[m][j];
            rsum[m] = 1.0f / S;
        }
        __syncthreads();
    }
    float acc[4][4];
#pragma unroll
    for (int i = 0; i < 4; ++i)
#pragma unroll
        for (int q = 0; q < 4; ++q) acc[i][q] = 0.f;
    for (int kt = 0; kt < 4; ++kt) {
#pragma unroll
        for (int it = 0; it < 4; ++it) {
            int idx = tid + 256 * it;
            int row = idx >> 5, c4 = (idx & 31) * 4;
            *(float4*)(&yt[row][c4]) =
                *(const float4*)(ys + ((long long)b * NP_ + kt * 32 + row) * D_ + d0 + c4);
        }
        __syncthreads();
#pragma unroll
        for (int k = 0; k < 32; ++k) {
            float4 y4 = *(const float4*)(&yt[k][tx * 4]);
            float c0 = lt[ty * 4 + 0][kt * 32 + k];
            float c1 = lt[ty * 4 + 1][kt * 32 + k];
            float c2 = lt[ty * 4 + 2][kt * 32 + k];
            float c3 = lt[ty * 4 + 3][kt * 32 + k];
            acc[0][0] += c0 * y4.x; acc[0][1] += c0 * y4.y; acc[0][2] += c0 * y4.z; acc[0][3] += c0 * y4.w;
            acc[1][0] += c1 * y4.x; acc[1][1] += c1 * y4.y; acc[1][2] += c1 * y4.z; acc[1][3] += c1 * y4.w;
            acc[2][0] += c2 * y4.x; acc[2][1] += c2 * y4.y; acc[2][2] += c2 * y4.z; acc[2][3] += c2 * y4.w;
            acc[3][0] += c3 * y4.x; acc[3][1] += c3 * y4.y; acc[3][2] += c3 * y4.z; acc[3][3] += c3 * y4.w;
        }
        __syncthreads();
    }
#pragma unroll
    for (int i = 0; i < 4; ++i) {
        int m = m0 + ty * 4 + i;
        float inv = rsum[ty * 4 + i];
        const float4 xv = *(const float4*)(x + ((long long)(b * M_ + m)) * D_ + d0 + tx * 4);
        float4 o;
        o.x = acc[i][0] * inv + xv.x;
        o.y = acc[i][1] * inv + xv.y;
        o.z = acc[i][2] * inv + xv.z;
        o.w = acc[i][3] * inv + xv.w;
        *(float4*)(out + ((long long)(b * M_ + m)) * D_ + d0 + tx * 4) = o;
    }
}

extern "C" void kernel_launch(void* const* d_in, const int* in_sizes, int n_in,
                              void* d_out, int out_size, void* d_ws, size_t ws_size,
                              hipStream_t stream) {
    const float* x = (const float*)d_in[0];
    const float* phi = (const float*)d_in[1];
    const float* scale = (const float*)d_in[2];
    const float* W = (const float*)d_in[3];
    const float* bias = (const float*)d_in[4];
    float* out = (float*)d_out;

    float* ws = (float*)d_ws;
    float* rinv = ws;                    // 32768
    float* phin = rinv + 32768;          // 131072
    float* logits = phin + 131072;       // 4194304
    float* pmax = logits + 4194304;      // 16384
    float* psum = pmax + 16384;          // 16384
    float* cmax = psum + 16384;          // 1024
    float* cinv = cmax + 1024;           // 1024
    float* dval = cinv + 1024;           // 4194304
    float* xs = dval + 4194304;          // 1048576
    float* ys = xs + 1048576;            // 1048576

    hipMemsetAsync(xs, 0, 1048576 * sizeof(float), stream);
    k_phin<<<128, 256, 0, stream>>>(phi, scale, phin);
    k_rownorm<<<8192, 256, 0, stream>>>(x, rinv);
    k_logits<<<dim3(64, 8), 256, 0, stream>>>(x, phin, rinv, logits);
    k_colstats1<<<dim3(16, 8), 256, 0, stream>>>(logits, pmax, psum);
    k_colstats2<<<8, 128, 0, stream>>>(pmax, psum, cmax, cinv);
    k_dval<<<4096, 256, 0, stream>>>(logits, cmax, cinv, dval);
    k_xs<<<dim3(16, 4, 8), 256, 0, stream>>>(x, dval, xs);
    k_ys<<<dim3(8, 64), 256, 0, stream>>>(xs, W, bias, ys);
    k_final<<<dim3(8, 128, 8), 256, 0, stream>>>(logits, ys, x, out);
}

// Round 2
// 655.170 us; speedup vs baseline: 1.4578x; 1.4578x over previous
//
#include <hip/hip_runtime.h>
#include <hip/hip_bf16.h>
#include <math.h>

#define B_ 8
#define M_ 4096
#define D_ 1024
#define NP_ 128
#define TEMP_ 0.1f
#define EPS_ 1e-12f

typedef __attribute__((ext_vector_type(8))) short bf16x8;
typedef __attribute__((ext_vector_type(4))) float f32x4;

__device__ __forceinline__ unsigned short f2bf(float f) {
    union { float f; unsigned int u; } v; v.f = f;
    unsigned int u = v.u;
    u += 0x7fff + ((u >> 16) & 1);  // RNE
    return (unsigned short)(u >> 16);
}

// stage 128 rows x 64 bytes into LDS (8 KB), via global_load_lds width 16.
// gbase points at (row0, k-byte-offset); row_stride in bytes.
__device__ __forceinline__ void stage_tile(const char* gbase, size_t row_stride,
                                           char* lds, int tid) {
    const int lane = tid & 63, w = tid >> 6;
#pragma unroll
    for (int t = 0; t < 2; ++t) {
        const int row = w * 32 + t * 16 + (lane >> 2);
        const char* g = gbase + (size_t)row * row_stride + (lane & 3) * 16;
        char* l = lds + (w * 32 + t * 16) * 64 + lane * 16;
        __builtin_amdgcn_global_load_lds((const __attribute__((address_space(1))) unsigned int*)g,
                                         (__attribute__((address_space(3))) unsigned int*)l,
                                         16, 0, 0);
    }
}

// ---------------- prep: rinv + bf16 cast (xbf[m][d]) + bf16 transpose (xbfT[d][m]) ----------------
__global__ __launch_bounds__(256) void k_prepT(const float* __restrict__ x,
                                               unsigned short* __restrict__ xbf,
                                               unsigned short* __restrict__ xbfT,
                                               float* __restrict__ rinv) {
    const int p = blockIdx.x;  // 512 = 8b * 8 m-panels... (B_*M_/64)
    const int b = p >> 6, m0 = (p & 63) * 64;
    const int tid = threadIdx.x;
    const int mg = tid >> 4;   // 0..15
    const int d4 = tid & 15;   // 0..15
    __shared__ unsigned short lt[64][72];  // [d][m], rows 144B (16B-aligned)
    float ss[4] = {0.f, 0.f, 0.f, 0.f};
    for (int ch = 0; ch < 16; ++ch) {
        const int d0 = ch * 64;
#pragma unroll
        for (int ii = 0; ii < 4; ++ii) {
            const int m = mg + ii * 16;
            float4 v = *(const float4*)(x + ((size_t)(b * M_ + m0 + m)) * D_ + d0 + d4 * 4);
            ss[ii] += v.x * v.x + v.y * v.y + v.z * v.z + v.w * v.w;
            ushort4 bv;
            bv.x = f2bf(v.x); bv.y = f2bf(v.y); bv.z = f2bf(v.z); bv.w = f2bf(v.w);
            *(ushort4*)(xbf + ((size_t)(b * M_ + m0 + m)) * D_ + d0 + d4 * 4) = bv;
            lt[d4 * 4 + 0][m] = bv.x;
            lt[d4 * 4 + 1][m] = bv.y;
            lt[d4 * 4 + 2][m] = bv.z;
            lt[d4 * 4 + 3][m] = bv.w;
        }
        __syncthreads();
        const int dl = tid >> 2, mq = (tid & 3) * 16;
        bf16x8 v0 = *(const bf16x8*)&lt[dl][mq];
        bf16x8 v1 = *(const bf16x8*)&lt[dl][mq + 8];
        unsigned short* to = xbfT + ((size_t)(b * D_ + d0 + dl)) * M_ + m0 + mq;
        *(bf16x8*)(to) = v0;
        *(bf16x8*)(to + 8) = v1;
        __syncthreads();
    }
#pragma unroll
    for (int ii = 0; ii < 4; ++ii) {
        float s = ss[ii];
        s += __shfl_down(s, 8, 16);
        s += __shfl_down(s, 4, 16);
        s += __shfl_down(s, 2, 16);
        s += __shfl_down(s, 1, 16);
        if (d4 == 0)
            rinv[b * M_ + m0 + mg + ii * 16] = 1.0f / (fmaxf(sqrtf(s), EPS_) * TEMP_);
    }
}

// ---------------- phi normalize -> phinT[np][d] bf16 ----------------
__global__ void k_phin(const float* __restrict__ phi, const float* __restrict__ scale,
                       unsigned short* __restrict__ phinT) {
    const int np = blockIdx.x, tid = threadIdx.x;
    float ss = 0.f;
    for (int d = tid; d < D_; d += 256) {
        float v = phi[d * NP_ + np];
        ss += v * v;
    }
    __shared__ float red[256];
    red[tid] = ss;
    __syncthreads();
    for (int s = 128; s > 0; s >>= 1) {
        if (tid < s) red[tid] += red[tid + s];
        __syncthreads();
    }
    float inv = scale[0] / fmaxf(sqrtf(red[0]), EPS_);
    for (int d = tid; d < D_; d += 256) phinT[np * D_ + d] = f2bf(phi[d * NP_ + np] * inv);
}

// ---------------- GEMM1: logitsT[b][np][m] = (phinT . xbf) * rinv[m] ----------------
__global__ __launch_bounds__(256) void k_logits(const unsigned short* __restrict__ phinT,
                                                const unsigned short* __restrict__ xbf,
                                                const float* __restrict__ rinv,
                                                float* __restrict__ logitsT) {
    const int b = blockIdx.y, m0 = blockIdx.x * 128;
    const int tid = threadIdx.x, lane = tid & 63, w = tid >> 6;
    __shared__ char At[8192], Bt[8192];
    f32x4 acc[4][4] = {};
    const char* abase = (const char*)phinT;  // 128 np rows, stride 2048 B
    const char* bbase = (const char*)(xbf + ((size_t)b * M_ + m0) * D_);  // stride 2048 B
    const int wm = (w & 1) * 64, wn = (w >> 1) * 64;
    const int fr = lane & 15, q = lane >> 4;
    for (int k0 = 0; k0 < D_ * 2; k0 += 64) {
        stage_tile(abase + k0, 2048, At, tid);
        stage_tile(bbase + k0, 2048, Bt, tid);
        __syncthreads();
        bf16x8 a[4], bb[4];
#pragma unroll
        for (int i = 0; i < 4; ++i)
            a[i] = *(const bf16x8*)(At + (wm + i * 16 + fr) * 64 + q * 16);
#pragma unroll
        for (int j = 0; j < 4; ++j)
            bb[j] = *(const bf16x8*)(Bt + (wn + j * 16 + fr) * 64 + q * 16);
#pragma unroll
        for (int i = 0; i < 4; ++i)
#pragma unroll
            for (int j = 0; j < 4; ++j)
                acc[i][j] = __builtin_amdgcn_mfma_f32_16x16x32_bf16(a[i], bb[j], acc[i][j], 0, 0, 0);
        __syncthreads();
    }
#pragma unroll
    for (int j = 0; j < 4; ++j) {
        const int m = m0 + wn + j * 16 + fr;
        const float r = rinv[b * M_ + m];
#pragma unroll
        for (int i = 0; i < 4; ++i) {
            const int nprow = wm + i * 16 + q * 4;
#pragma unroll
            for (int reg = 0; reg < 4; ++reg)
                logitsT[((size_t)b * NP_ + nprow + reg) * M_ + m] = acc[i][j][reg] * r;
        }
    }
}

// ---------------- dispatch softmax stats over m (rows of logitsT) ----------------
__global__ void k_colstats(const float* __restrict__ logitsT, float* __restrict__ cmax,
                           float* __restrict__ cinv) {
    const int row = blockIdx.x * 4 + (threadIdx.x >> 6);  // b*128+np
    const int lane = threadIdx.x & 63;
    const float4* base = (const float4*)(logitsT + (size_t)row * M_);
    float mx = -1e30f, sm = 0.f;
#pragma unroll 4
    for (int it = 0; it < 16; ++it) {
        float4 v = base[lane + 64 * it];
        float lm = fmaxf(fmaxf(v.x, v.y), fmaxf(v.z, v.w));
        float nm = fmaxf(mx, lm);
        sm = sm * __expf(mx - nm) + __expf(v.x - nm) + __expf(v.y - nm) + __expf(v.z - nm) +
             __expf(v.w - nm);
        mx = nm;
    }
    for (int off = 32; off > 0; off >>= 1) {
        float om = __shfl_down(mx, off), os = __shfl_down(sm, off);
        float nm = fmaxf(mx, om);
        sm = sm * __expf(mx - nm) + os * __expf(om - nm);
        mx = nm;
    }
    if (lane == 0) {
        cmax[row] = mx;
        cinv[row] = 1.0f / sm;
    }
}

// ---------------- weights: dvalT[np][m] bf16 (dispatch), cbf[m][np] bf16 (combine) ----------------
__global__ __launch_bounds__(256) void k_weights(const float* __restrict__ logitsT,
                                                 const float* __restrict__ cmax,
                                                 const float* __restrict__ cinv,
                                                 unsigned short* __restrict__ dvalT,
                                                 unsigned short* __restrict__ cbf) {
    const int b = blockIdx.y, m0 = blockIdx.x * 32;
    const int tid = threadIdx.x;
    __shared__ float lt[128][36];
    __shared__ float red[32][8];
    __shared__ float rstat[32][2];
    const int np = tid >> 1;
    const int mh = (tid & 1) * 16;
    const float cm = cmax[b * NP_ + np], ci = cinv[b * NP_ + np];
#pragma unroll
    for (int ii = 0; ii < 4; ++ii) {
        const int mq = mh + ii * 4;
        float4 v = *(const float4*)(logitsT + ((size_t)b * NP_ + np) * M_ + m0 + mq);
        *(float4*)&lt[np][mq] = v;
        ushort4 e;
        e.x = f2bf(__expf(v.x - cm) * ci);
        e.y = f2bf(__expf(v.y - cm) * ci);
        e.z = f2bf(__expf(v.z - cm) * ci);
        e.w = f2bf(__expf(v.w - cm) * ci);
        *(ushort4*)(dvalT + ((size_t)b * NP_ + np) * M_ + m0 + mq) = e;
    }
    __syncthreads();
    const int mm = tid >> 3, g = tid & 7;
    float mx = -1e30f;
#pragma unroll
    for (int i = 0; i < 16; ++i) mx = fmaxf(mx, lt[g * 16 + i][mm]);
    red[mm][g] = mx;
    __syncthreads();
    if (g == 0) {
        float M2 = red[mm][0];
#pragma unroll
        for (int k = 1; k < 8; ++k) M2 = fmaxf(M2, red[mm][k]);
        rstat[mm][0] = M2;
    }
    __syncthreads();
    const float rm = rstat[mm][0];
    float s = 0.f;
#pragma unroll
    for (int i = 0; i < 16; ++i) s += __expf(lt[g * 16 + i][mm] - rm);
    red[mm][g] = s;
    __syncthreads();
    if (g == 0) {
        float S = 0.f;
#pragma unroll
        for (int k = 0; k < 8; ++k) S += red[mm][k];
        rstat[mm][1] = 1.0f / S;
    }
    __syncthreads();
    const float ri = rstat[mm][1];
    bf16x8 o0, o1;
#pragma unroll
    for (int i = 0; i < 8; ++i) o0[i] = (short)f2bf(__expf(lt[g * 16 + i][mm] - rm) * ri);
#pragma unroll
    for (int i = 0; i < 8; ++i) o1[i] = (short)f2bf(__expf(lt[g * 16 + 8 + i][mm] - rm) * ri);
    unsigned short* co = cbf + ((size_t)b * M_ + m0 + mm) * NP_ + g * 16;
    *(bf16x8*)(co) = o0;
    *(bf16x8*)(co + 8) = o1;
}

// ---------------- GEMM2: partial[kc][b][np][d] = dvalT-chunk . xbfT-chunk ----------------
__global__ __launch_bounds__(256) void k_xs(const unsigned short* __restrict__ dvalT,
                                            const unsigned short* __restrict__ xbfT,
                                            float* __restrict__ partial) {
    const int dt = blockIdx.x, kc = blockIdx.y, b = blockIdx.z;
    const int d0 = dt * 128;
    const int tid = threadIdx.x, lane = tid & 63, w = tid >> 6;
    __shared__ char At[8192], Bt[8192];
    f32x4 acc[4][4] = {};
    const char* abase = (const char*)(dvalT + (size_t)b * NP_ * M_) + (size_t)kc * 2048;
    const char* bbase = (const char*)(xbfT + ((size_t)b * D_ + d0) * M_) + (size_t)kc * 2048;
    const int wm = (w & 1) * 64, wn = (w >> 1) * 64;
    const int fr = lane & 15, q = lane >> 4;
    for (int k0 = 0; k0 < 2048; k0 += 64) {
        stage_tile(abase + k0, (size_t)M_ * 2, At, tid);
        stage_tile(bbase + k0, (size_t)M_ * 2, Bt, tid);
        __syncthreads();
        bf16x8 a[4], bb[4];
#pragma unroll
        for (int i = 0; i < 4; ++i)
            a[i] = *(const bf16x8*)(At + (wm + i * 16 + fr) * 64 + q * 16);
#pragma unroll
        for (int j = 0; j < 4; ++j)
            bb[j] = *(const bf16x8*)(Bt + (wn + j * 16 + fr) * 64 + q * 16);
#pragma unroll
        for (int i = 0; i < 4; ++i)
#pragma unroll
            for (int j = 0; j < 4; ++j)
                acc[i][j] = __builtin_amdgcn_mfma_f32_16x16x32_bf16(a[i], bb[j], acc[i][j], 0, 0, 0);
        __syncthreads();
    }
#pragma unroll
    for (int j = 0; j < 4; ++j) {
        const int d = d0 + wn + j * 16 + fr;
#pragma unroll
        for (int i = 0; i < 4; ++i) {
            const int nprow = wm + i * 16 + q * 4;
#pragma unroll
            for (int reg = 0; reg < 4; ++reg)
                partial[(((size_t)kc * B_ + b) * NP_ + nprow + reg) * D_ + d] = acc[i][j][reg];
        }
    }
}

// ---------------- reduce split-K partials -> xs[b][np][d] fp32 ----------------
__global__ void k_xsred(const float* __restrict__ partial, float* __restrict__ xs) {
    const size_t i = ((size_t)blockIdx.x * 256 + threadIdx.x) * 4;
    const size_t CH = (size_t)B_ * NP_ * D_;
    float4 s0 = *(const float4*)(partial + i);
    float4 s1 = *(const float4*)(partial + CH + i);
    float4 s2 = *(const float4*)(partial + 2 * CH + i);
    float4 s3 = *(const float4*)(partial + 3 * CH + i);
    float4 o;
    o.x = s0.x + s1.x + s2.x + s3.x;
    o.y = s0.y + s1.y + s2.y + s3.y;
    o.z = s0.z + s1.z + s2.z + s3.z;
    o.w = s0.w + s1.w + s2.w + s3.w;
    *(float4*)(xs + i) = o;
}

// ---------------- per-expert linear: ysT[b][e][np] bf16 = xs @ W[n] + bias[n] ----------------
__global__ __launch_bounds__(256) void k_ys(const float* __restrict__ xs,
                                            const float* __restrict__ W,
                                            const float* __restrict__ bias,
                                            unsigned short* __restrict__ ysT) {
    const int et = blockIdx.x;  // 8 tiles of 128 e
    const int n = blockIdx.y;   // 64
    const int e0 = et * 128;
    const int tid = threadIdx.x, tx = tid & 31, ty = tid >> 5;
    __shared__ float wt[32][128];
    __shared__ float xst[16][32];
    float acc[2][4];
#pragma unroll
    for (int j = 0; j < 2; ++j)
#pragma unroll
        for (int q = 0; q < 4; ++q) acc[j][q] = 0.f;
    const float* wbase = W + (size_t)n * D_ * D_;
    for (int k0 = 0; k0 < D_; k0 += 32) {
#pragma unroll
        for (int it = 0; it < 4; ++it) {
            int idx = tid + 256 * it;
            int row = idx >> 5, c4 = (idx & 31) * 4;
            *(float4*)(&wt[row][c4]) = *(const float4*)(wbase + (size_t)(k0 + row) * D_ + e0 + c4);
        }
        if (tid < 128) {
            int r = tid >> 3, c4 = (tid & 7) * 4;
            int bb = r >> 1, pp = r & 1;
            *(float4*)(&xst[r][c4]) =
                *(const float4*)(xs + ((size_t)bb * NP_ + n * 2 + pp) * D_ + k0 + c4);
        }
        __syncthreads();
#pragma unroll
        for (int k = 0; k < 32; ++k) {
            float4 w4 = *(const float4*)(&wt[k][tx * 4]);
            float r0 = xst[ty * 2][k], r1 = xst[ty * 2 + 1][k];
            acc[0][0] += r0 * w4.x; acc[0][1] += r0 * w4.y;
            acc[0][2] += r0 * w4.z; acc[0][3] += r0 * w4.w;
            acc[1][0] += r1 * w4.x; acc[1][1] += r1 * w4.y;
            acc[1][2] += r1 * w4.z; acc[1][3] += r1 * w4.w;
        }
        __syncthreads();
    }
    float4 bv = *(const float4*)(bias + n * D_ + e0 + tx * 4);
#pragma unroll
    for (int j = 0; j < 2; ++j) {
        const int r = ty * 2 + j;
        const int bb = r >> 1, pp = r & 1;
        float v0 = acc[j][0] + bv.x, v1 = acc[j][1] + bv.y;
        float v2 = acc[j][2] + bv.z, v3 = acc[j][3] + bv.w;
        ysT[((size_t)bb * D_ + e0 + tx * 4 + 0) * NP_ + n * 2 + pp] = f2bf(v0);
        ysT[((size_t)bb * D_ + e0 + tx * 4 + 1) * NP_ + n * 2 + pp] = f2bf(v1);
        ysT[((size_t)bb * D_ + e0 + tx * 4 + 2) * NP_ + n * 2 + pp] = f2bf(v2);
        ysT[((size_t)bb * D_ + e0 + tx * 4 + 3) * NP_ + n * 2 + pp] = f2bf(v3);
    }
}

// ---------------- GEMM3: out[b][m][e] = cbf . ysT + x ----------------
__global__ __launch_bounds__(256) void k_final(const unsigned short* __restrict__ cbf,
                                               const unsigned short* __restrict__ ysT,
                                               const float* __restrict__ x,
                                               float* __restrict__ out) {
    const int et = blockIdx.x, mt = blockIdx.y, b = blockIdx.z;
    const int e0 = et * 128, m0 = mt * 128;
    const int tid = threadIdx.x, lane = tid & 63, w = tid >> 6;
    __shared__ char At[8192], Bt[8192];
    f32x4 acc[4][4] = {};
    const char* abase = (const char*)(cbf + ((size_t)b * M_ + m0) * NP_);  // stride 256 B
    const char* bbase = (const char*)(ysT + ((size_t)b * D_ + e0) * NP_);  // stride 256 B
    const int wm = (w & 1) * 64, wn = (w >> 1) * 64;
    const int fr = lane & 15, q = lane >> 4;
    for (int k0 = 0; k0 < 256; k0 += 64) {
        stage_tile(abase + k0, 256, At, tid);
        stage_tile(bbase + k0, 256, Bt, tid);
        __syncthreads();
        bf16x8 a[4], bb[4];
#pragma unroll
        for (int i = 0; i < 4; ++i)
            a[i] = *(const bf16x8*)(At + (wm + i * 16 + fr) * 64 + q * 16);
#pragma unroll
        for (int j = 0; j < 4; ++j)
            bb[j] = *(const bf16x8*)(Bt + (wn + j * 16 + fr) * 64 + q * 16);
#pragma unroll
        for (int i = 0; i < 4; ++i)
#pragma unroll
            for (int j = 0; j < 4; ++j)
                acc[i][j] = __builtin_amdgcn_mfma_f32_16x16x32_bf16(a[i], bb[j], acc[i][j], 0, 0, 0);
        __syncthreads();
    }
#pragma unroll
    for (int i = 0; i < 4; ++i) {
#pragma unroll
        for (int reg = 0; reg < 4; ++reg) {
            const int m = m0 + wm + i * 16 + q * 4 + reg;
#pragma unroll
            for (int j = 0; j < 4; ++j) {
                const int e = e0 + wn + j * 16 + fr;
                const size_t idx = ((size_t)b * M_ + m) * D_ + e;
                out[idx] = acc[i][j][reg] + x[idx];
            }
        }
    }
}

extern "C" void kernel_launch(void* const* d_in, const int* in_sizes, int n_in,
                              void* d_out, int out_size, void* d_ws, size_t ws_size,
                              hipStream_t stream) {
    const float* x = (const float*)d_in[0];
    const float* phi = (const float*)d_in[1];
    const float* scale = (const float*)d_in[2];
    const float* W = (const float*)d_in[3];
    const float* bias = (const float*)d_in[4];
    float* out = (float*)d_out;

    char* ws = (char*)d_ws;
    float* rinv = (float*)ws;                                   // 131072 B
    float* cmax = (float*)(ws + 131072);                        // 4096 B
    float* cinv = (float*)(ws + 135168);                        // 4096 B
    unsigned short* phinT = (unsigned short*)(ws + 139264);     // 262144 B
    unsigned short* xbf = (unsigned short*)(ws + 401408);       // 64 MiB
    unsigned short* xbfT = (unsigned short*)(ws + 401408 + 67108864);   // 64 MiB
    float* logitsT = (float*)(ws + 401408 + 134217728);         // 16 MiB
    unsigned short* dvalT = (unsigned short*)(ws + 401408 + 150994944);  // 8 MiB
    unsigned short* cbf = (unsigned short*)(ws + 401408 + 159383552);    // 8 MiB
    // aliases (lifetime-disjoint):
    float* partial = logitsT;            // 16 MiB, after k_weights is done with logitsT
    float* xs = (float*)xbf;             // 4 MiB, after k_logits is done with xbf
    unsigned short* ysT = (unsigned short*)((char*)xbf + 4194304);  // 2 MiB

    k_prepT<<<512, 256, 0, stream>>>(x, xbf, xbfT, rinv);
    k_phin<<<128, 256, 0, stream>>>(phi, scale, phinT);
    k_logits<<<dim3(32, 8), 256, 0, stream>>>(phinT, xbf, rinv, logitsT);
    k_colstats<<<256, 256, 0, stream>>>(logitsT, cmax, cinv);
    k_weights<<<dim3(128, 8), 256, 0, stream>>>(logitsT, cmax, cinv, dvalT, cbf);
    k_xs<<<dim3(8, 4, 8), 256, 0, stream>>>(dvalT, xbfT, partial);
    k_xsred<<<1024, 256, 0, stream>>>(partial, xs);
    k_ys<<<dim3(8, 64), 256, 0, stream>>>(xs, W, bias, ysT);
    k_final<<<dim3(8, 32, 8), 256, 0, stream>>>(cbf, ysT, x, out);
}